// Round 18
// baseline (486.298 us; speedup 1.0000x reference)
//
#include <hip/hip_runtime.h>
#include <hip/hip_fp16.h>

#define NN 20000      // nodes
#define NE 320000     // edges
#define SS 2          // feature axis
#define FIN 128
#define FH 246

typedef _Float16 f16x8 __attribute__((ext_vector_type(8)));
typedef float f32x4 __attribute__((ext_vector_type(4)));

// ---------------- degree histogram ----------------
__global__ void degree_kernel(const int* __restrict__ src, const int* __restrict__ dst,
                              int* __restrict__ deg_out, int* __restrict__ deg_in) {
    int e = blockIdx.x * blockDim.x + threadIdx.x;
    if (e < NE) {
        atomicAdd(&deg_out[src[e]], 1);
        atomicAdd(&deg_in[dst[e]], 1);
    }
}

// ---------------- norms + parallel CSR range allocation (fused) ----------------
__global__ void alloc_kernel(const int* __restrict__ deg_out, const int* __restrict__ deg_in,
                             float* __restrict__ norm_out, float* __restrict__ norm_in,
                             int* __restrict__ row_start, int* __restrict__ cursor,
                             int* __restrict__ counter, int* __restrict__ dhist) {
    __shared__ int smem[256];
    __shared__ int base_s;
    int tid = threadIdx.x;
    int i = blockIdx.x * 256 + tid;
    int v = (i < NN) ? deg_in[i] : 0;
    smem[tid] = v;
    __syncthreads();
    for (int off = 1; off < 256; off <<= 1) {
        int t = (tid >= off) ? smem[tid - off] : 0;
        __syncthreads();
        smem[tid] += t;
        __syncthreads();
    }
    int incl = smem[tid];
    if (tid == 0) base_s = atomicAdd(counter, smem[255]);
    __syncthreads();
    if (i < NN) {
        int excl = base_s + incl - v;
        row_start[i] = excl;
        cursor[i]    = excl;
        norm_out[i] = rsqrtf(fmaxf((float)deg_out[i], 1.0f));
        norm_in[i]  = rsqrtf(fmaxf((float)v, 1.0f));
        atomicAdd(&dhist[min(v, 255)], 1);   // degree histogram for counting sort
    }
}

// ---------------- degree-bin exclusive scan (1 block) ----------------
__global__ void binscan_kernel(const int* __restrict__ dhist, int* __restrict__ bincur) {
    __shared__ int smem[256];
    int tid = threadIdx.x;
    int v = dhist[tid];
    smem[tid] = v;
    __syncthreads();
    for (int off = 1; off < 256; off <<= 1) {
        int t = (tid >= off) ? smem[tid - off] : 0;
        __syncthreads();
        smem[tid] += t;
        __syncthreads();
    }
    bincur[tid] = smem[tid] - v;   // exclusive prefix
}

// ---------------- counting-sort scatter: perm = nodes sorted by in-degree ----------
// Blocks of 8 degree-adjacent nodes minimize exec-mask waste in the aggregate
// (max-of-8 ~ mean instead of ~1.4x mean). Per-node math order unchanged ->
// output bitwise identical regardless of perm order within a bin.
__global__ void permute_kernel(const int* __restrict__ deg_in, int* __restrict__ bincur,
                               int* __restrict__ perm) {
    int i = blockIdx.x * 256 + threadIdx.x;
    if (i < NN) {
        int p = atomicAdd(&bincur[min(deg_in[i], 255)], 1);
        perm[p] = i;
    }
}

// ---------------- scatter edges into CSR ----------------
__global__ void scatter_kernel(const int* __restrict__ src, const int* __restrict__ dst,
                               int* __restrict__ cursor, int* __restrict__ sorted_src) {
    int e = blockIdx.x * blockDim.x + threadIdx.x;
    if (e < NE) {
        int d = dst[e];
        int pos = atomicAdd(&cursor[d], 1);
        sorted_src[pos] = src[e];
    }
}

// ---------------- W pre-split (all 3 layers in one launch) ----------------
__global__ void convert_w_all(const float* __restrict__ W0, const float* __restrict__ W1,
                              const float* __restrict__ W2,
                              ushort* __restrict__ Wh0, ushort* __restrict__ Wl0,
                              ushort* __restrict__ Wh1, ushort* __restrict__ Wl1,
                              ushort* __restrict__ Wh2, ushort* __restrict__ Wl2) {
    int n = blockIdx.x, k = threadIdx.x;
    const float* W; ushort* Wh; ushort* Wl; int K;
    if (blockIdx.y == 0)      { W = W0; Wh = Wh0; Wl = Wl0; K = FIN; }
    else if (blockIdx.y == 1) { W = W1; Wh = Wh1; Wl = Wl1; K = FH; }
    else                      { W = W2; Wh = Wh2; Wl = Wl2; K = FH; }
    float v = (k < K && n < 246) ? W[k * 246 + n] : 0.f;
    _Float16 h = (_Float16)v;
    _Float16 l = (_Float16)(v - (float)h);
    Wh[n * 256 + k] = *(ushort*)&h;
    Wl[n * 256 + k] = *(ushort*)&l;
}

__global__ void init_out(float* __restrict__ out, const float* __restrict__ fcb) {
    int i = blockIdx.x * 256 + threadIdx.x;
    if (i < NN) out[i] = fcb[0];
}

// ---------------- XCD-pinned, degree-sorted gather-aggregate, split-f16 out ----------
// agg[n,:] = norm_in[n] * sum_{e: dst=n} h[src,:]*norm_out[src], output split to
// f16 hi/lo (Ah, Al). XCD PINNING (round-16: FETCH 235->115 MB): chunk =
// blockIdx.x % NCH; round-robin block->XCD dispatch keeps each XCD on one ~5 MB
// column slice. DEGREE SORT (round-18): the 8 nodes of a block come from perm[]
// (in-degree sorted) so their edge loops are near-equal length. 4x edge unroll
// (8x regressed: round 17). 128 threads = 8 nodes x 16 lanes.
template<int F4ROW, int NCH>
__global__ void aggregate2(const float* __restrict__ h,
                           const int* __restrict__ row_start,
                           const int* __restrict__ deg_in,
                           const int* __restrict__ sorted_src,
                           const int* __restrict__ perm,
                           const float* __restrict__ norm_out,
                           const float* __restrict__ norm_in,
                           ushort* __restrict__ Ah, ushort* __restrict__ Al) {
    int g  = threadIdx.x >> 4;              // 0..7: node sub-index
    int l  = threadIdx.x & 15;              // float4 within chunk
    int cb = blockIdx.x & (NCH - 1);        // chunk (XCD-pinned axis)
    int nb = blockIdx.x / NCH;              // node group
    int ni_ = nb * 8 + g;
    if (ni_ >= NN) return;
    int n = perm[ni_];                      // degree-sorted node id
    int idx = cb * 16 + l;                  // < F4ROW (= NCH*16)
    const float4* hv = (const float4*)h;
    int beg = row_start[n];
    int end = beg + deg_in[n];
    float4 acc = {0.f, 0.f, 0.f, 0.f};
    int i = beg;
    for (; i + 4 <= end; i += 4) {
        int s0 = sorted_src[i + 0];
        int s1 = sorted_src[i + 1];
        int s2 = sorted_src[i + 2];
        int s3 = sorted_src[i + 3];
        float n0 = norm_out[s0], n1 = norm_out[s1];
        float n2 = norm_out[s2], n3 = norm_out[s3];
        float4 v0 = hv[(size_t)s0 * F4ROW + idx];
        float4 v1 = hv[(size_t)s1 * F4ROW + idx];
        float4 v2 = hv[(size_t)s2 * F4ROW + idx];
        float4 v3 = hv[(size_t)s3 * F4ROW + idx];
        acc.x += v0.x * n0 + v1.x * n1 + v2.x * n2 + v3.x * n3;
        acc.y += v0.y * n0 + v1.y * n1 + v2.y * n2 + v3.y * n3;
        acc.z += v0.z * n0 + v1.z * n1 + v2.z * n2 + v3.z * n3;
        acc.w += v0.w * n0 + v1.w * n1 + v2.w * n2 + v3.w * n3;
    }
    for (; i < end; ++i) {
        int s = sorted_src[i];
        float nr = norm_out[s];
        float4 v = hv[(size_t)s * F4ROW + idx];
        acc.x += v.x * nr;
        acc.y += v.y * nr;
        acc.z += v.z * nr;
        acc.w += v.w * nr;
    }
    float ni = norm_in[n];
    float v[4] = {acc.x * ni, acc.y * ni, acc.z * ni, acc.w * ni};
    ushort hp[4], lp[4];
#pragma unroll
    for (int j = 0; j < 4; ++j) {
        _Float16 hh = (_Float16)v[j];
        _Float16 ll = (_Float16)(v[j] - (float)hh);
        hp[j] = *(ushort*)&hh;
        lp[j] = *(ushort*)&ll;
    }
    ((uint2*)Ah)[(size_t)n * F4ROW + idx] = *(uint2*)hp;
    ((uint2*)Al)[(size_t)n * F4ROW + idx] = *(uint2*)lp;
}

// ---------------- split-f16 MFMA GEMM, pre-split A (round-14, known-good) ----------
// D[m,c] = relu( A[m,:] . W[:,c] + b[c] ), A = pre-split f16 hi/lo [40000][KP]
// (KP=128|256, k-pads zero, norm_in folded), W pre-split f16 hi/lo [256][256].
// Block 64M x 128N, 4 waves 2x2, wave tile 32x64 via 2x4 mfma_f32_16x16x32_f16;
// acc += Ah*Wh + Al*Wh + Ah*Wl. Grid (625, 2). No VALU in the K-loop.
// FUSE: relu -> *fc_w -> mean_s -> 16-lane reduce -> atomicAdd(out[node], 0.5p).
template<int KP, bool FUSE>
__global__ __launch_bounds__(256) void gemm_split(const ushort* __restrict__ Ah,
                                                  const ushort* __restrict__ Al,
                                                  const ushort* __restrict__ Wh,
                                                  const ushort* __restrict__ Wl,
                                                  const float* __restrict__ b,
                                                  void* __restrict__ outv,
                                                  const float* __restrict__ fcw) {
    constexpr int NT = KP / 32;
    constexpr int AS = KP / 8;             // A row stride in uint4
    __shared__ __align__(16) _Float16 Ah_s[64][40];
    __shared__ __align__(16) _Float16 Al_s[64][40];
    __shared__ __align__(16) _Float16 Bh_s[128][40];
    __shared__ __align__(16) _Float16 Bl_s[128][40];

    int tid  = threadIdx.x;
    int m0   = blockIdx.x * 64;
    int n0   = blockIdx.y * 128;
    int wave = tid >> 6, lane = tid & 63;
    int wm = wave >> 1, wn = wave & 1;
    int lr = lane & 15, quad = lane >> 4;

    f32x4 acc[2][4];
#pragma unroll
    for (int mi = 0; mi < 2; ++mi)
#pragma unroll
        for (int ni = 0; ni < 4; ++ni) acc[mi][ni] = {0.f, 0.f, 0.f, 0.f};

    int ar = tid >> 2;                 // A row 0..63
    int aq = tid & 3;                  // uint4 within 64B k-tile
    const uint4* Ahv = (const uint4*)Ah;
    const uint4* Alv = (const uint4*)Al;
    const uint4* Whv = (const uint4*)Wh;   // row stride 32 uint4
    const uint4* Wlv = (const uint4*)Wl;

    for (int t0 = 0; t0 < NT; ++t0) {
        // ---- stage A: 64 rows x 32 k, hi+lo (1 uint4/thread each), pure copy
        size_t abase = (size_t)(m0 + ar) * AS + t0 * 4 + aq;
        *(uint4*)&Ah_s[ar][aq * 8] = Ahv[abase];
        *(uint4*)&Al_s[ar][aq * 8] = Alv[abase];
        // ---- stage B: 128 rows x 32 k, hi+lo (2 uint4/thread each)
#pragma unroll
        for (int it = 0; it < 2; ++it) {
            int f = it * 256 + tid;
            int rn = f >> 2, q = f & 3;
            size_t base = (size_t)(n0 + rn) * 32 + t0 * 4 + q;
            *(uint4*)&Bh_s[rn][q * 8] = Whv[base];
            *(uint4*)&Bl_s[rn][q * 8] = Wlv[base];
        }
        __syncthreads();

        f16x8 ah[2], al[2], bh[4], bl[4];
#pragma unroll
        for (int mi = 0; mi < 2; ++mi) {
            ah[mi] = *(const f16x8*)&Ah_s[wm * 32 + mi * 16 + lr][quad * 8];
            al[mi] = *(const f16x8*)&Al_s[wm * 32 + mi * 16 + lr][quad * 8];
        }
#pragma unroll
        for (int ni = 0; ni < 4; ++ni) {
            bh[ni] = *(const f16x8*)&Bh_s[wn * 64 + ni * 16 + lr][quad * 8];
            bl[ni] = *(const f16x8*)&Bl_s[wn * 64 + ni * 16 + lr][quad * 8];
        }
#pragma unroll
        for (int mi = 0; mi < 2; ++mi)
#pragma unroll
            for (int ni = 0; ni < 4; ++ni) {
                acc[mi][ni] = __builtin_amdgcn_mfma_f32_16x16x32_f16(ah[mi], bh[ni], acc[mi][ni], 0, 0, 0);
                acc[mi][ni] = __builtin_amdgcn_mfma_f32_16x16x32_f16(al[mi], bh[ni], acc[mi][ni], 0, 0, 0);
                acc[mi][ni] = __builtin_amdgcn_mfma_f32_16x16x32_f16(ah[mi], bl[ni], acc[mi][ni], 0, 0, 0);
            }
        __syncthreads();
    }

    if (FUSE) {
        float* out = (float*)outv;
#pragma unroll
        for (int mi = 0; mi < 2; ++mi) {
#pragma unroll
            for (int i = 0; i < 4; ++i) {
                float p = 0.f;
#pragma unroll
                for (int ni = 0; ni < 4; ++ni) {
                    int c = n0 + wn * 64 + ni * 16 + lr;
                    if (c < 246)
                        p += fmaxf(acc[mi][ni][i] + b[c], 0.f) * fcw[c];
                }
#pragma unroll
                for (int off = 8; off > 0; off >>= 1)
                    p += __shfl_down(p, off, 16);
                if (lr == 0) {
                    int m = m0 + wm * 32 + mi * 16 + quad * 4 + i;
                    atomicAdd(&out[m >> 1], 0.5f * p);
                }
            }
        }
    } else {
        float* outF = (float*)outv;    // fp32 [M][256]; cols>=246 get 0 (acc=0, bj=0)
#pragma unroll
        for (int ni = 0; ni < 4; ++ni) {
            int c = n0 + wn * 64 + ni * 16 + lr;
            float bj = (c < 246) ? b[c] : 0.f;
#pragma unroll
            for (int mi = 0; mi < 2; ++mi)
#pragma unroll
                for (int i = 0; i < 4; ++i) {
                    int m = m0 + wm * 32 + mi * 16 + quad * 4 + i;
                    outF[(size_t)m * 256 + c] = fmaxf(acc[mi][ni][i] + bj, 0.f);
                }
        }
    }
}

extern "C" void kernel_launch(void* const* d_in, const int* in_sizes, int n_in,
                              void* d_out, int out_size, void* d_ws, size_t ws_size,
                              hipStream_t stream) {
    const float* feat = (const float*)d_in[0];
    const int*   src  = (const int*)d_in[1];
    const int*   dst  = (const int*)d_in[2];
    const float* W0   = (const float*)d_in[3];
    const float* b0   = (const float*)d_in[4];
    const float* W1   = (const float*)d_in[5];
    const float* b1   = (const float*)d_in[6];
    const float* W2   = (const float*)d_in[7];
    const float* b2   = (const float*)d_in[8];
    const float* fcw  = (const float*)d_in[9];
    const float* fcb  = (const float*)d_in[10];
    float* out = (float*)d_out;

    char* ws = (char*)d_ws;
    size_t off = 0;
    auto alloc = [&](size_t bytes) {
        void* p = ws + off;
        off = (off + bytes + 255) & ~(size_t)255;
        return p;
    };
    // deg_out, deg_in, counter(+pad), dhist(256) all zeroed in one memset
    int*    deg_out_i = (int*)alloc((2 * NN + 64 + 256) * sizeof(int));
    int*    deg_in_i  = deg_out_i + NN;
    int*    counter   = deg_out_i + 2 * NN;
    int*    dhist     = deg_out_i + 2 * NN + 64;
    int*    bincur    = (int*)alloc(256 * sizeof(int));
    int*    perm      = (int*)alloc(NN * sizeof(int));
    int*    row_start = (int*)alloc(NN * sizeof(int));
    int*    cursor    = (int*)alloc(NN * sizeof(int));
    int*    sorted    = (int*)alloc(NE * sizeof(int));
    float*  norm_out  = (float*)alloc(NN * sizeof(float));
    float*  norm_in   = (float*)alloc(NN * sizeof(float));
    ushort* Wh0 = (ushort*)alloc(256 * 256 * sizeof(ushort));
    ushort* Wl0 = (ushort*)alloc(256 * 256 * sizeof(ushort));
    ushort* Wh1 = (ushort*)alloc(256 * 256 * sizeof(ushort));
    ushort* Wl1 = (ushort*)alloc(256 * 256 * sizeof(ushort));
    ushort* Wh2 = (ushort*)alloc(256 * 256 * sizeof(ushort));
    ushort* Wl2 = (ushort*)alloc(256 * 256 * sizeof(ushort));
    ushort* Ahb = (ushort*)alloc((size_t)NN * SS * 256 * sizeof(ushort));  // split A hi
    ushort* Alb = (ushort*)alloc((size_t)NN * SS * 256 * sizeof(ushort));  // split A lo
    float*  bufH = (float*)alloc((size_t)NN * SS * 256 * sizeof(float));   // gemm out (padded)

    hipMemsetAsync(deg_out_i, 0, (2 * NN + 64 + 256) * sizeof(int), stream);

    degree_kernel<<<(NE + 255) / 256, 256, 0, stream>>>(src, dst, deg_out_i, deg_in_i);
    alloc_kernel<<<(NN + 255) / 256, 256, 0, stream>>>(deg_out_i, deg_in_i, norm_out, norm_in,
                                                       row_start, cursor, counter, dhist);
    binscan_kernel<<<1, 256, 0, stream>>>(dhist, bincur);
    permute_kernel<<<(NN + 255) / 256, 256, 0, stream>>>(deg_in_i, bincur, perm);
    scatter_kernel<<<(NE + 255) / 256, 256, 0, stream>>>(src, dst, cursor, sorted);

    convert_w_all<<<dim3(256, 3), 256, 0, stream>>>(W0, W1, W2, Wh0, Wl0, Wh1, Wl1, Wh2, Wl2);
    init_out<<<(NN + 255) / 256, 256, 0, stream>>>(out, fcb);

    const int NB8 = (NN + 7) / 8;    // 2500 node groups (8 nodes/block)
    dim3 ggrid(NN * SS / 64, 2);     // 625 x 2

    // Layer 0: feat [N][2*128] -> agg+split (chunk = blk%4) -> gemm -> h1(bufH, 256)
    aggregate2<64, 4><<<NB8 * 4, 128, 0, stream>>>(feat, row_start, deg_in_i, sorted, perm,
                                                   norm_out, norm_in, Ahb, Alb);
    gemm_split<FIN, false><<<ggrid, 256, 0, stream>>>(Ahb, Alb, Wh0, Wl0, b0, bufH, fcw);

    // Layer 1: h1 -> agg+split (chunk = blk%8) -> gemm -> h2(bufH)
    aggregate2<128, 8><<<NB8 * 8, 128, 0, stream>>>(bufH, row_start, deg_in_i, sorted, perm,
                                                    norm_out, norm_in, Ahb, Alb);
    gemm_split<256, false><<<ggrid, 256, 0, stream>>>(Ahb, Alb, Wh1, Wl1, b1, bufH, fcw);

    // Layer 2: h2 -> agg+split -> fused gemm -> out (atomicAdd; out pre-set to fcb)
    aggregate2<128, 8><<<NB8 * 8, 128, 0, stream>>>(bufH, row_start, deg_in_i, sorted, perm,
                                                    norm_out, norm_in, Ahb, Alb);
    gemm_split<256, true><<<ggrid, 256, 0, stream>>>(Ahb, Alb, Wh2, Wl2, b2, out, fcw);
}

// Round 19
// 368.382 us; speedup vs baseline: 1.3201x; 1.3201x over previous
//
#include <hip/hip_runtime.h>
#include <hip/hip_fp16.h>

#define NN 20000      // nodes
#define NE 320000     // edges
#define SS 2          // feature axis
#define FIN 128
#define FH 246

typedef _Float16 f16x8 __attribute__((ext_vector_type(8)));
typedef float f32x4 __attribute__((ext_vector_type(4)));

// ---------------- degree histogram ----------------
__global__ void degree_kernel(const int* __restrict__ src, const int* __restrict__ dst,
                              int* __restrict__ deg_out, int* __restrict__ deg_in) {
    int e = blockIdx.x * blockDim.x + threadIdx.x;
    if (e < NE) {
        atomicAdd(&deg_out[src[e]], 1);
        atomicAdd(&deg_in[dst[e]], 1);
    }
}

// ---------------- norms + parallel CSR range allocation (fused) ----------------
__global__ void alloc_kernel(const int* __restrict__ deg_out, const int* __restrict__ deg_in,
                             float* __restrict__ norm_out, float* __restrict__ norm_in,
                             int* __restrict__ row_start, int* __restrict__ cursor,
                             int* __restrict__ counter) {
    __shared__ int smem[256];
    __shared__ int base_s;
    int tid = threadIdx.x;
    int i = blockIdx.x * 256 + tid;
    int v = (i < NN) ? deg_in[i] : 0;
    smem[tid] = v;
    __syncthreads();
    for (int off = 1; off < 256; off <<= 1) {
        int t = (tid >= off) ? smem[tid - off] : 0;
        __syncthreads();
        smem[tid] += t;
        __syncthreads();
    }
    int incl = smem[tid];
    if (tid == 0) base_s = atomicAdd(counter, smem[255]);
    __syncthreads();
    if (i < NN) {
        int excl = base_s + incl - v;
        row_start[i] = excl;
        cursor[i]    = excl;
        norm_out[i] = rsqrtf(fmaxf((float)deg_out[i], 1.0f));
        norm_in[i]  = rsqrtf(fmaxf((float)v, 1.0f));
    }
}

// ---------------- scatter edges into CSR ----------------
__global__ void scatter_kernel(const int* __restrict__ src, const int* __restrict__ dst,
                               int* __restrict__ cursor, int* __restrict__ sorted_src) {
    int e = blockIdx.x * blockDim.x + threadIdx.x;
    if (e < NE) {
        int d = dst[e];
        int pos = atomicAdd(&cursor[d], 1);
        sorted_src[pos] = src[e];
    }
}

// ---------------- W pre-split (all 3 layers in one launch) ----------------
__global__ void convert_w_all(const float* __restrict__ W0, const float* __restrict__ W1,
                              const float* __restrict__ W2,
                              ushort* __restrict__ Wh0, ushort* __restrict__ Wl0,
                              ushort* __restrict__ Wh1, ushort* __restrict__ Wl1,
                              ushort* __restrict__ Wh2, ushort* __restrict__ Wl2) {
    int n = blockIdx.x, k = threadIdx.x;
    const float* W; ushort* Wh; ushort* Wl; int K;
    if (blockIdx.y == 0)      { W = W0; Wh = Wh0; Wl = Wl0; K = FIN; }
    else if (blockIdx.y == 1) { W = W1; Wh = Wh1; Wl = Wl1; K = FH; }
    else                      { W = W2; Wh = Wh2; Wl = Wl2; K = FH; }
    float v = (k < K && n < 246) ? W[k * 246 + n] : 0.f;
    _Float16 h = (_Float16)v;
    _Float16 l = (_Float16)(v - (float)h);
    Wh[n * 256 + k] = *(ushort*)&h;
    Wl[n * 256 + k] = *(ushort*)&l;
}

__global__ void init_out(float* __restrict__ out, const float* __restrict__ fcb) {
    int i = blockIdx.x * 256 + threadIdx.x;
    if (i < NN) out[i] = fcb[0];
}

// ---------------- XCD-pinned chunk-tiled gather-aggregate, split-f16 output ----------
// agg[n,:] = norm_in[n] * sum_{e: dst=n} h[src,:]*norm_out[src], output split to
// f16 hi/lo (Ah, Al). XCD PINNING (round-16 win: FETCH 235->115 MB): chunk =
// blockIdx.x % NCH; with round-robin block->XCD dispatch, each XCD gathers from
// one ~5 MB column slice (~L2-resident). 4x edge unroll (8x regressed: r17;
// degree-sort node assignment regressed: r18 -- locality beats divergence).
// 128 threads = 8 nodes x 16 lanes; lane owns float4 #(chunk*16+l).
template<int F4ROW, int NCH>
__global__ void aggregate2(const float* __restrict__ h,
                           const int* __restrict__ row_start,
                           const int* __restrict__ deg_in,
                           const int* __restrict__ sorted_src,
                           const float* __restrict__ norm_out,
                           const float* __restrict__ norm_in,
                           ushort* __restrict__ Ah, ushort* __restrict__ Al) {
    int g  = threadIdx.x >> 4;              // 0..7: node sub-index
    int l  = threadIdx.x & 15;              // float4 within chunk
    int cb = blockIdx.x & (NCH - 1);        // chunk (XCD-pinned axis)
    int nb = blockIdx.x / NCH;              // node group
    int n  = nb * 8 + g;
    if (n >= NN) return;
    int idx = cb * 16 + l;                  // < F4ROW (= NCH*16)
    const float4* hv = (const float4*)h;
    int beg = row_start[n];
    int end = beg + deg_in[n];
    float4 acc = {0.f, 0.f, 0.f, 0.f};
    int i = beg;
    for (; i + 4 <= end; i += 4) {
        int s0 = sorted_src[i + 0];
        int s1 = sorted_src[i + 1];
        int s2 = sorted_src[i + 2];
        int s3 = sorted_src[i + 3];
        float n0 = norm_out[s0], n1 = norm_out[s1];
        float n2 = norm_out[s2], n3 = norm_out[s3];
        float4 v0 = hv[(size_t)s0 * F4ROW + idx];
        float4 v1 = hv[(size_t)s1 * F4ROW + idx];
        float4 v2 = hv[(size_t)s2 * F4ROW + idx];
        float4 v3 = hv[(size_t)s3 * F4ROW + idx];
        acc.x += v0.x * n0 + v1.x * n1 + v2.x * n2 + v3.x * n3;
        acc.y += v0.y * n0 + v1.y * n1 + v2.y * n2 + v3.y * n3;
        acc.z += v0.z * n0 + v1.z * n1 + v2.z * n2 + v3.z * n3;
        acc.w += v0.w * n0 + v1.w * n1 + v2.w * n2 + v3.w * n3;
    }
    for (; i < end; ++i) {
        int s = sorted_src[i];
        float nr = norm_out[s];
        float4 v = hv[(size_t)s * F4ROW + idx];
        acc.x += v.x * nr;
        acc.y += v.y * nr;
        acc.z += v.z * nr;
        acc.w += v.w * nr;
    }
    float ni = norm_in[n];
    float v[4] = {acc.x * ni, acc.y * ni, acc.z * ni, acc.w * ni};
    ushort hp[4], lp[4];
#pragma unroll
    for (int j = 0; j < 4; ++j) {
        _Float16 hh = (_Float16)v[j];
        _Float16 ll = (_Float16)(v[j] - (float)hh);
        hp[j] = *(ushort*)&hh;
        lp[j] = *(ushort*)&ll;
    }
    ((uint2*)Ah)[(size_t)n * F4ROW + idx] = *(uint2*)hp;
    ((uint2*)Al)[(size_t)n * F4ROW + idx] = *(uint2*)lp;
}

// ---------------- split-f16 MFMA GEMM, pre-split A (round-14, known-good) ----------
// D[m,c] = relu( A[m,:] . W[:,c] + b[c] ), A = pre-split f16 hi/lo [40000][KP]
// (KP=128|256, k-pads zero, norm_in folded), W pre-split f16 hi/lo [256][256].
// Block 64M x 128N, 4 waves 2x2, wave tile 32x64 via 2x4 mfma_f32_16x16x32_f16;
// acc += Ah*Wh + Al*Wh + Ah*Wl. Grid (625, 2). No VALU in the K-loop.
// FUSE: relu -> *fc_w -> mean_s -> 16-lane reduce -> atomicAdd(out[node], 0.5p).
template<int KP, bool FUSE>
__global__ __launch_bounds__(256) void gemm_split(const ushort* __restrict__ Ah,
                                                  const ushort* __restrict__ Al,
                                                  const ushort* __restrict__ Wh,
                                                  const ushort* __restrict__ Wl,
                                                  const float* __restrict__ b,
                                                  void* __restrict__ outv,
                                                  const float* __restrict__ fcw) {
    constexpr int NT = KP / 32;
    constexpr int AS = KP / 8;             // A row stride in uint4
    __shared__ __align__(16) _Float16 Ah_s[64][40];
    __shared__ __align__(16) _Float16 Al_s[64][40];
    __shared__ __align__(16) _Float16 Bh_s[128][40];
    __shared__ __align__(16) _Float16 Bl_s[128][40];

    int tid  = threadIdx.x;
    int m0   = blockIdx.x * 64;
    int n0   = blockIdx.y * 128;
    int wave = tid >> 6, lane = tid & 63;
    int wm = wave >> 1, wn = wave & 1;
    int lr = lane & 15, quad = lane >> 4;

    f32x4 acc[2][4];
#pragma unroll
    for (int mi = 0; mi < 2; ++mi)
#pragma unroll
        for (int ni = 0; ni < 4; ++ni) acc[mi][ni] = {0.f, 0.f, 0.f, 0.f};

    int ar = tid >> 2;                 // A row 0..63
    int aq = tid & 3;                  // uint4 within 64B k-tile
    const uint4* Ahv = (const uint4*)Ah;
    const uint4* Alv = (const uint4*)Al;
    const uint4* Whv = (const uint4*)Wh;   // row stride 32 uint4
    const uint4* Wlv = (const uint4*)Wl;

    for (int t0 = 0; t0 < NT; ++t0) {
        // ---- stage A: 64 rows x 32 k, hi+lo (1 uint4/thread each), pure copy
        size_t abase = (size_t)(m0 + ar) * AS + t0 * 4 + aq;
        *(uint4*)&Ah_s[ar][aq * 8] = Ahv[abase];
        *(uint4*)&Al_s[ar][aq * 8] = Alv[abase];
        // ---- stage B: 128 rows x 32 k, hi+lo (2 uint4/thread each)
#pragma unroll
        for (int it = 0; it < 2; ++it) {
            int f = it * 256 + tid;
            int rn = f >> 2, q = f & 3;
            size_t base = (size_t)(n0 + rn) * 32 + t0 * 4 + q;
            *(uint4*)&Bh_s[rn][q * 8] = Whv[base];
            *(uint4*)&Bl_s[rn][q * 8] = Wlv[base];
        }
        __syncthreads();

        f16x8 ah[2], al[2], bh[4], bl[4];
#pragma unroll
        for (int mi = 0; mi < 2; ++mi) {
            ah[mi] = *(const f16x8*)&Ah_s[wm * 32 + mi * 16 + lr][quad * 8];
            al[mi] = *(const f16x8*)&Al_s[wm * 32 + mi * 16 + lr][quad * 8];
        }
#pragma unroll
        for (int ni = 0; ni < 4; ++ni) {
            bh[ni] = *(const f16x8*)&Bh_s[wn * 64 + ni * 16 + lr][quad * 8];
            bl[ni] = *(const f16x8*)&Bl_s[wn * 64 + ni * 16 + lr][quad * 8];
        }
#pragma unroll
        for (int mi = 0; mi < 2; ++mi)
#pragma unroll
            for (int ni = 0; ni < 4; ++ni) {
                acc[mi][ni] = __builtin_amdgcn_mfma_f32_16x16x32_f16(ah[mi], bh[ni], acc[mi][ni], 0, 0, 0);
                acc[mi][ni] = __builtin_amdgcn_mfma_f32_16x16x32_f16(al[mi], bh[ni], acc[mi][ni], 0, 0, 0);
                acc[mi][ni] = __builtin_amdgcn_mfma_f32_16x16x32_f16(ah[mi], bl[ni], acc[mi][ni], 0, 0, 0);
            }
        __syncthreads();
    }

    if (FUSE) {
        float* out = (float*)outv;
#pragma unroll
        for (int mi = 0; mi < 2; ++mi) {
#pragma unroll
            for (int i = 0; i < 4; ++i) {
                float p = 0.f;
#pragma unroll
                for (int ni = 0; ni < 4; ++ni) {
                    int c = n0 + wn * 64 + ni * 16 + lr;
                    if (c < 246)
                        p += fmaxf(acc[mi][ni][i] + b[c], 0.f) * fcw[c];
                }
#pragma unroll
                for (int off = 8; off > 0; off >>= 1)
                    p += __shfl_down(p, off, 16);
                if (lr == 0) {
                    int m = m0 + wm * 32 + mi * 16 + quad * 4 + i;
                    atomicAdd(&out[m >> 1], 0.5f * p);
                }
            }
        }
    } else {
        float* outF = (float*)outv;    // fp32 [M][256]; cols>=246 get 0 (acc=0, bj=0)
#pragma unroll
        for (int ni = 0; ni < 4; ++ni) {
            int c = n0 + wn * 64 + ni * 16 + lr;
            float bj = (c < 246) ? b[c] : 0.f;
#pragma unroll
            for (int mi = 0; mi < 2; ++mi)
#pragma unroll
                for (int i = 0; i < 4; ++i) {
                    int m = m0 + wm * 32 + mi * 16 + quad * 4 + i;
                    outF[(size_t)m * 256 + c] = fmaxf(acc[mi][ni][i] + bj, 0.f);
                }
        }
    }
}

extern "C" void kernel_launch(void* const* d_in, const int* in_sizes, int n_in,
                              void* d_out, int out_size, void* d_ws, size_t ws_size,
                              hipStream_t stream) {
    const float* feat = (const float*)d_in[0];
    const int*   src  = (const int*)d_in[1];
    const int*   dst  = (const int*)d_in[2];
    const float* W0   = (const float*)d_in[3];
    const float* b0   = (const float*)d_in[4];
    const float* W1   = (const float*)d_in[5];
    const float* b1   = (const float*)d_in[6];
    const float* W2   = (const float*)d_in[7];
    const float* b2   = (const float*)d_in[8];
    const float* fcw  = (const float*)d_in[9];
    const float* fcb  = (const float*)d_in[10];
    float* out = (float*)d_out;

    char* ws = (char*)d_ws;
    size_t off = 0;
    auto alloc = [&](size_t bytes) {
        void* p = ws + off;
        off = (off + bytes + 255) & ~(size_t)255;
        return p;
    };
    int*    deg_out_i = (int*)alloc((2 * NN + 64) * sizeof(int));
    int*    deg_in_i  = deg_out_i + NN;
    int*    counter   = deg_out_i + 2 * NN;
    int*    row_start = (int*)alloc(NN * sizeof(int));
    int*    cursor    = (int*)alloc(NN * sizeof(int));
    int*    sorted    = (int*)alloc(NE * sizeof(int));
    float*  norm_out  = (float*)alloc(NN * sizeof(float));
    float*  norm_in   = (float*)alloc(NN * sizeof(float));
    ushort* Wh0 = (ushort*)alloc(256 * 256 * sizeof(ushort));
    ushort* Wl0 = (ushort*)alloc(256 * 256 * sizeof(ushort));
    ushort* Wh1 = (ushort*)alloc(256 * 256 * sizeof(ushort));
    ushort* Wl1 = (ushort*)alloc(256 * 256 * sizeof(ushort));
    ushort* Wh2 = (ushort*)alloc(256 * 256 * sizeof(ushort));
    ushort* Wl2 = (ushort*)alloc(256 * 256 * sizeof(ushort));
    ushort* Ahb = (ushort*)alloc((size_t)NN * SS * 256 * sizeof(ushort));  // split A hi
    ushort* Alb = (ushort*)alloc((size_t)NN * SS * 256 * sizeof(ushort));  // split A lo
    float*  bufH = (float*)alloc((size_t)NN * SS * 256 * sizeof(float));   // gemm out (padded)

    hipMemsetAsync(deg_out_i, 0, (2 * NN + 1) * sizeof(int), stream);

    degree_kernel<<<(NE + 255) / 256, 256, 0, stream>>>(src, dst, deg_out_i, deg_in_i);
    alloc_kernel<<<(NN + 255) / 256, 256, 0, stream>>>(deg_out_i, deg_in_i, norm_out, norm_in,
                                                       row_start, cursor, counter);
    scatter_kernel<<<(NE + 255) / 256, 256, 0, stream>>>(src, dst, cursor, sorted);

    convert_w_all<<<dim3(256, 3), 256, 0, stream>>>(W0, W1, W2, Wh0, Wl0, Wh1, Wl1, Wh2, Wl2);
    init_out<<<(NN + 255) / 256, 256, 0, stream>>>(out, fcb);

    const int NB8 = (NN + 7) / 8;    // 2500 node groups (8 nodes/block)
    dim3 ggrid(NN * SS / 64, 2);     // 625 x 2

    // Layer 0: feat [N][2*128] -> agg+split (chunk = blk%4) -> gemm -> h1(bufH, 256)
    aggregate2<64, 4><<<NB8 * 4, 128, 0, stream>>>(feat, row_start, deg_in_i, sorted,
                                                   norm_out, norm_in, Ahb, Alb);
    gemm_split<FIN, false><<<ggrid, 256, 0, stream>>>(Ahb, Alb, Wh0, Wl0, b0, bufH, fcw);

    // Layer 1: h1 -> agg+split (chunk = blk%8) -> gemm -> h2(bufH)
    aggregate2<128, 8><<<NB8 * 8, 128, 0, stream>>>(bufH, row_start, deg_in_i, sorted,
                                                    norm_out, norm_in, Ahb, Alb);
    gemm_split<256, false><<<ggrid, 256, 0, stream>>>(Ahb, Alb, Wh1, Wl1, b1, bufH, fcw);

    // Layer 2: h2 -> agg+split -> fused gemm -> out (atomicAdd; out pre-set to fcb)
    aggregate2<128, 8><<<NB8 * 8, 128, 0, stream>>>(bufH, row_start, deg_in_i, sorted,
                                                    norm_out, norm_in, Ahb, Alb);
    gemm_split<256, true><<<ggrid, 256, 0, stream>>>(Ahb, Alb, Wh2, Wl2, b2, out, fcw);
}